// Round 7
// baseline (791.911 us; speedup 1.0000x reference)
//
#include <hip/hip_runtime.h>
#include <hip/hip_bf16.h>
#include <stdint.h>

typedef __bf16 bf16_t;
typedef bf16_t bf16x8 __attribute__((ext_vector_type(8)));
typedef float f32x4 __attribute__((ext_vector_type(4)));

static constexpr int B_TOK  = 4096;
static constexpr int E_DIM  = 1024;
static constexpr int N_EXPC = 8;
static constexpr int HID    = 4096;
static constexpr int IMGSZ  = 4096;
static constexpr int NSLOT  = 2 * B_TOK;
static constexpr int MAXT2  = 40;          // sum ceil(cnt_e/256) <= 32+7, pad to 40

#define DEVI __device__ __forceinline__

DEVI int imin(int a, int b) { return a < b ? a : b; }

DEVI uint16_t f2bf(float f) {
  union { float f; uint32_t u; } v; v.f = f;
  uint32_t u = v.u;
  return (uint16_t)((u + 0x7FFFu + ((u >> 16) & 1u)) >> 16);
}

DEVI void gload_lds16(const void* g, void* l) {
  __builtin_amdgcn_global_load_lds((const __attribute__((address_space(1))) void*)g,
                                   (__attribute__((address_space(3))) void*)l, 16, 0, 0);
}

template<int N> DEVI void waitv() {
  if constexpr (N == 0)       asm volatile("s_waitcnt vmcnt(0)" ::: "memory");
  else if constexpr (N == 4)  asm volatile("s_waitcnt vmcnt(4)" ::: "memory");
  else if constexpr (N == 5)  asm volatile("s_waitcnt vmcnt(5)" ::: "memory");
  else if constexpr (N == 8)  asm volatile("s_waitcnt vmcnt(8)" ::: "memory");
  else if constexpr (N == 10) asm volatile("s_waitcnt vmcnt(10)" ::: "memory");
}

#define BAR() do { __builtin_amdgcn_sched_barrier(0); __builtin_amdgcn_s_barrier(); \
                   __builtin_amdgcn_sched_barrier(0); } while (0)

#define MFMA16(a, b, c) __builtin_amdgcn_mfma_f32_16x16x32_bf16((a), (b), (c), 0, 0, 0)

// ---------------- transpose + convert: f32 [R][C] -> bf16 [C][R], 64x64 tiles ----------------
__global__ __launch_bounds__(256)
void transpose64(const float* __restrict__ in, uint16_t* __restrict__ out, int R, int C)
{
  __shared__ float tile[64][65];
  size_t off = (size_t)blockIdx.z * (size_t)R * (size_t)C;
  int c0 = blockIdx.x * 64, r0 = blockIdx.y * 64;
  int t = threadIdx.x;
  #pragma unroll
  for (int i = 0; i < 16; ++i) {
    int rr = i * 4 + (t >> 6), cc = t & 63;
    tile[rr][cc] = in[off + (size_t)(r0 + rr) * C + c0 + cc];
  }
  __syncthreads();
  #pragma unroll
  for (int i = 0; i < 8; ++i) {
    int c = i * 8 + (t >> 5), j = t & 31;
    ushort2 w;
    w.x = f2bf(tile[2 * j][c]);
    w.y = f2bf(tile[2 * j + 1][c]);
    *(ushort2*)&out[off + (size_t)(c0 + c) * R + r0 + 2 * j] = w;
  }
}

// ================= 256x256 expert GEMM — m201-form 4-phase schedule, deep ledger =================
// C[rows,N] = A[gathered rows, K] @ BT[N,K]^T; 8 waves (2M x 4N), BK=64.
// Half-tiles per K-tile: h0=A-ks0, h1=B-ks0, h2=A-ks1, h3=B-ks1 (2 gloads each).
// Staging: P0(kt) stages {h0,h1}(kt+1); P1(kt) stages {h2,h3}(kt+1); P2/P3 none.
// Gates (derived, in-order retirement; max 12 in flight):
//   P1: vmcnt(8)  -> retires A1B1(kt)   (issued P1(kt-1), 4-phase lead)
//   P3: vmcnt(4)  -> retires A0B0(kt+1) (issued P0(kt),   3-phase lead)
//   last tile: P1 -> vmcnt(0), P3 -> no gate.
// Per phase: {ds_read 4A [+4B if Q==0]; stage; gate; BAR; lgkm0; setprio1; 16 MFMA; setprio0; BAR}.
// LDS: [2 buf][2 ks][256 rows][64 B] per operand (64 KB x2); slice-XOR swizzle (r>>1)&3.
// EPI: 0 = raw f32 (no bias; split-K partial), 3 = bias + gelu -> bf16
template<int EPI, bool GATHER, int NT, int KSPLIT>
__global__ __launch_bounds__(512, 2)
void gemm256(const uint16_t* __restrict__ A,
             const uint16_t* __restrict__ BT, void* __restrict__ Cv, int ldc,
             const float* __restrict__ bias, int Kfull,
             const int* __restrict__ meta, const int* __restrict__ perm,
             size_t bStride, int biasStride, size_t cPlane)
{
  constexpr int NWG = MAXT2 * NT * KSPLIT;
  int bid = blockIdx.x;
  int wg = (bid & 7) * (NWG / 8) + (bid >> 3);     // bijective XCD swizzle (NWG%8==0)
  int mtile = wg % MAXT2;
  int rest  = wg / MAXT2;
  int nt = rest % NT, kc = rest / NT;
  if (mtile >= meta[0]) return;
  int e = meta[1 + 3 * mtile], rowBase = meta[2 + 3 * mtile], rows = meta[3 + 3 * mtile];
  int K = Kfull / KSPLIT, k0 = kc * K;
  const uint16_t* Bt = BT + (size_t)e * bStride;
  const float* bi = bias + (size_t)e * (size_t)biasStride + nt * 256;

  __shared__ __align__(16) uint16_t sA[2 * 2 * 256 * 32];   // 64 KB
  __shared__ __align__(16) uint16_t sB[2 * 2 * 256 * 32];   // 64 KB
  char* sAc = (char*)sA;
  char* sBc = (char*)sB;

  int t = threadIdx.x, wave = t >> 6, lane = t & 63;
  int wm = wave >> 2, wn = wave & 3;
  int rr = t >> 2;                                 // 0..127 (row within half-tile load)
  int sg = (t & 3) ^ ((t >> 3) & 3);               // pre-swizzled global 16B slice
  int a0r = imin(rr, rows - 1), a1r = imin(128 + rr, rows - 1);
  int ca0 = GATHER ? perm[rowBase + a0r] : rowBase + a0r;
  int ca1 = GATHER ? perm[rowBase + a1r] : rowBase + a1r;
  const uint16_t* gA0 = A + (size_t)ca0 * Kfull + k0 + sg * 8;
  const uint16_t* gA1 = A + (size_t)ca1 * Kfull + k0 + sg * 8;
  const uint16_t* gB0 = Bt + (size_t)(nt * 256 + rr) * Kfull + k0 + sg * 8;
  const uint16_t* gB1 = gB0 + (size_t)128 * Kfull;
  int wO = wave * 1024;

  f32x4 acc[8][4];
  #pragma unroll
  for (int m = 0; m < 8; ++m)
    #pragma unroll
    for (int n = 0; n < 4; ++n)
      acc[m][n] = f32x4{0.f, 0.f, 0.f, 0.f};

  int fr = lane & 15, q4 = lane >> 4;
  int xsl = (q4 ^ ((fr >> 1) & 3)) * 16;           // read-side slice XOR (2-way = free)
  int aRd = (wm * 128 + fr) * 64 + xsl;
  int bRd = (wn * 64 + fr) * 64 + xsl;

#define STGA(kt_, nb_, ks_) do { int go_ = (kt_) * 64 + (ks_) * 32; \
    gload_lds16(gA0 + go_, sAc + (nb_) * 32768 + (ks_) * 16384 + wO); \
    gload_lds16(gA1 + go_, sAc + (nb_) * 32768 + (ks_) * 16384 + 8192 + wO); } while (0)
#define STGB(kt_, nb_, ks_) do { int go_ = (kt_) * 64 + (ks_) * 32; \
    gload_lds16(gB0 + go_, sBc + (nb_) * 32768 + (ks_) * 16384 + wO); \
    gload_lds16(gB1 + go_, sBc + (nb_) * 32768 + (ks_) * 16384 + 8192 + wO); } while (0)
#define RDA(m_, ks_) (*(const bf16x8*)(sAc + bufOff + (ks_) * 16384 + aRd + (m_) * 1024))
#define RDB(n_, ks_) (*(const bf16x8*)(sBc + bufOff + (ks_) * 16384 + bRd + (n_) * 1024))
#define PH(KS, Q, STGST, GATEST) do { \
    if ((Q) == 0) { bfr[0] = RDB(0, KS); bfr[1] = RDB(1, KS); \
                    bfr[2] = RDB(2, KS); bfr[3] = RDB(3, KS); } \
    bf16x8 a0_ = RDA(4 * (Q) + 0, KS), a1_ = RDA(4 * (Q) + 1, KS), \
           a2_ = RDA(4 * (Q) + 2, KS), a3_ = RDA(4 * (Q) + 3, KS); \
    STGST; \
    GATEST; \
    __builtin_amdgcn_sched_barrier(0); \
    __builtin_amdgcn_s_barrier(); \
    asm volatile("s_waitcnt lgkmcnt(0)" ::: "memory"); \
    __builtin_amdgcn_sched_barrier(0); \
    __builtin_amdgcn_s_setprio(1); \
    _Pragma("unroll") \
    for (int n_ = 0; n_ < 4; ++n_) { \
      acc[4 * (Q) + 0][n_] = MFMA16(a0_, bfr[n_], acc[4 * (Q) + 0][n_]); \
      acc[4 * (Q) + 1][n_] = MFMA16(a1_, bfr[n_], acc[4 * (Q) + 1][n_]); \
      acc[4 * (Q) + 2][n_] = MFMA16(a2_, bfr[n_], acc[4 * (Q) + 2][n_]); \
      acc[4 * (Q) + 3][n_] = MFMA16(a3_, bfr[n_], acc[4 * (Q) + 3][n_]); } \
    __builtin_amdgcn_s_setprio(0); \
    __builtin_amdgcn_s_barrier(); \
  } while (0)

  // prologue: tile 0's four half-tiles; vmcnt(4) lands h0,h1 (h2,h3 gated at P1(0))
  STGA(0, 0, 0); STGB(0, 0, 0); STGA(0, 0, 1); STGB(0, 0, 1);
  waitv<4>();
  __builtin_amdgcn_s_barrier();

  bf16x8 bfr[4];
  int nk = K >> 6;
  for (int kt = 0; kt < nk; ++kt) {
    int buf = kt & 1, nb = buf ^ 1;
    int bufOff = buf * 32768;
    bool more = kt + 1 < nk;
    PH(0, 0, if (more) { STGA(kt + 1, nb, 0); STGB(kt + 1, nb, 0); }, (void)0);
    PH(0, 1, if (more) { STGA(kt + 1, nb, 1); STGB(kt + 1, nb, 1); },
             if (more) waitv<8>(); else waitv<0>());
    PH(1, 0, (void)0, (void)0);
    PH(1, 1, (void)0, if (more) waitv<4>());
  }
#undef STGA
#undef STGB
#undef RDA
#undef RDB
#undef PH

  // epilogue: C/D layout col=lane&15, row=(lane>>4)*4+reg (m89-verified)
  #pragma unroll
  for (int m = 0; m < 8; ++m) {
    int lrb = wm * 128 + m * 16 + q4 * 4;
    #pragma unroll
    for (int n = 0; n < 4; ++n) {
      int col = wn * 64 + n * 16 + fr;
      float bval = (EPI == 3) ? bi[col] : 0.f;
      int gcol = nt * 256 + col;
      #pragma unroll
      for (int r = 0; r < 4; ++r) {
        int lr = lrb + r;
        if (lr >= rows) continue;
        float v = acc[m][n][r] + bval;
        size_t off = (size_t)kc * cPlane + (size_t)(rowBase + lr) * ldc + gcol;
        if (EPI == 3) {   // gelu(tanh) == v * sigmoid(1.5957691*(v + 0.044715 v^3))
          float u = v + 0.044715f * v * v * v;
          v = v / (1.f + __expf(-1.5957691216057308f * u));
          ((uint16_t*)Cv)[off] = f2bf(v);
        } else {
          ((float*)Cv)[off] = v;
        }
      }
    }
  }
}

// ================= enc/img GEMM: f32-A staged raw, split-K, f32 partial out =================
template<int SPLITK>
__global__ __launch_bounds__(256, 2)
void gemm_enc(const float* __restrict__ F0, const float* __restrict__ F1,
              const float* __restrict__ F2, int lda,
              const uint16_t* __restrict__ BT, float* __restrict__ P, int K)
{
  int z = blockIdx.z, br = z / SPLITK, kc = z % SPLITK;
  const float* Af = (br == 0) ? F0 : (br == 1) ? F1 : F2;
  int Kc = K / SPLITK, k0 = kc * Kc;
  int rowBase = blockIdx.x * 128, nt = blockIdx.y;

  constexpr int ABUF = 16384, BBUF = 4096;
  __shared__ __align__(16) char sAraw[3 * ABUF];
  __shared__ __align__(16) char sBraw[3 * BBUF];

  int t = threadIdx.x, wave = t >> 6, lane = t & 63;
  int wr = wave >> 1, wc = wave & 1;

  int rB = t >> 2;
  int slB = ((t & 3) ^ (rB & 3)) * 8;
  const uint16_t* gB0 = BT + (size_t)(nt * 64 + rB) * K + k0 + slB;

  const float* gF[4];
  int g = (t & 7) ^ ((t >> 3) & 7);
  #pragma unroll
  for (int i = 0; i < 4; ++i) {
    int r = i * 32 + (t >> 3);
    gF[i] = Af + (size_t)(rowBase + r) * lda + k0 + g * 4;
  }

  char* laW = sAraw + wave * 1024;
  char* lbW = sBraw + wave * 1024;
  auto STAGE = [&](int kt, int c) {
    int ko = kt << 5;
    char* la = laW + c * ABUF;
    char* lb = lbW + c * BBUF;
    #pragma unroll
    for (int i = 0; i < 4; ++i)
      gload_lds16(gF[i] + ko, la + i * 4096);
    gload_lds16(gB0 + ko, lb);
  };

  f32x4 acc[4][2];
  #pragma unroll
  for (int m = 0; m < 4; m++)
    #pragma unroll
    for (int n = 0; n < 2; n++)
      acc[m][n] = f32x4{0.f, 0.f, 0.f, 0.f};

  STAGE(0, 0);
  STAGE(1, 1);

  int fr = lane & 15;
  int rdoff = ((lane >> 4) ^ (lane & 3)) * 16;
  int c0 = 0, c2 = 2;
  int nk = Kc >> 5;

  for (int kt = 0; kt < nk; ++kt) {
    if (kt + 2 < nk) { STAGE(kt + 2, c2); waitv<10>(); }
    else if (kt + 1 < nk) waitv<5>();
    else waitv<0>();
    BAR();

    const char* bA = sAraw + c0 * ABUF;
    const char* bB = sBraw + c0 * BBUF;
    bf16x8 af[4], bfr[2];
    #pragma unroll
    for (int m = 0; m < 4; m++) {
      int rrow = wr * 64 + m * 16 + fr;
      int slot0 = ((lane >> 4) * 2) ^ (rrow & 7);
      f32x4 lo = *(const f32x4*)(bA + rrow * 128 + slot0 * 16);
      f32x4 hi = *(const f32x4*)(bA + rrow * 128 + (slot0 ^ 1) * 16);
      bf16x8 v;
      v[0] = (bf16_t)lo[0]; v[1] = (bf16_t)lo[1]; v[2] = (bf16_t)lo[2]; v[3] = (bf16_t)lo[3];
      v[4] = (bf16_t)hi[0]; v[5] = (bf16_t)hi[1]; v[6] = (bf16_t)hi[2]; v[7] = (bf16_t)hi[3];
      af[m] = v;
    }
    #pragma unroll
    for (int n = 0; n < 2; n++)
      bfr[n] = *(const bf16x8*)(bB + (wc * 32 + n * 16 + fr) * 64 + rdoff);
    #pragma unroll
    for (int m = 0; m < 4; m++)
      #pragma unroll
      for (int n = 0; n < 2; n++)
        acc[m][n] = MFMA16(af[m], bfr[n], acc[m][n]);

    BAR();
    c0 = (c0 == 2) ? 0 : c0 + 1;
    c2 = (c2 == 2) ? 0 : c2 + 1;
  }

  #pragma unroll
  for (int m = 0; m < 4; m++) {
    int lrow = wr * 64 + m * 16 + (lane >> 4) * 4;
    #pragma unroll
    for (int n = 0; n < 2; n++) {
      int col = nt * 64 + wc * 32 + n * 16 + fr;
      #pragma unroll
      for (int r = 0; r < 4; r++) {
        int grow = rowBase + lrow + r;
        P[((size_t)z * B_TOK + grow) * 256 + col] = acc[m][n][r];
      }
    }
  }
}

// reduce split-K partials + bias (+silu) -> bf16 columns of xbf
template<int SK, bool SILU>
__global__ __launch_bounds__(256)
void redu_k(const float* __restrict__ P, const float* __restrict__ bias,
            uint16_t* __restrict__ xb, int colBase)
{
  int br = blockIdx.y;
  int row = blockIdx.x * 4 + (threadIdx.x >> 6);
  int c4 = (threadIdx.x & 63) * 4;
  f32x4 s = *(const f32x4*)&bias[c4];
  const float* p = P + ((size_t)br * SK * B_TOK + row) * 256 + c4;
  #pragma unroll
  for (int kc = 0; kc < SK; ++kc)
    s += *(const f32x4*)(p + (size_t)kc * B_TOK * 256);
  if (SILU) {
    #pragma unroll
    for (int j = 0; j < 4; ++j) s[j] = s[j] / (1.f + __expf(-s[j]));
  }
  ushort4 o;
  o.x = f2bf(s[0]); o.y = f2bf(s[1]); o.z = f2bf(s[2]); o.w = f2bf(s[3]);
  *(ushort4*)&xb[(size_t)row * E_DIM + colBase + br * 256 + c4] = o;
}

// ---------------- gate-path fold (all f32, parallelized) ----------------
__global__ __launch_bounds__(256)
void bvwo_k(const float* __restrict__ bv, const float* __restrict__ Wo,
            float* __restrict__ part)
{
  int b = blockIdx.x, t = threadIdx.x;
  f32x4 acc = {0.f, 0.f, 0.f, 0.f};
  for (int k = b * 128; k < b * 128 + 128; ++k) {
    float s = bv[k];
    f32x4 w = *(const f32x4*)&Wo[(size_t)k * E_DIM + t * 4];
    acc[0] = __builtin_fmaf(s, w[0], acc[0]);
    acc[1] = __builtin_fmaf(s, w[1], acc[1]);
    acc[2] = __builtin_fmaf(s, w[2], acc[2]);
    acc[3] = __builtin_fmaf(s, w[3], acc[3]);
  }
  *(f32x4*)&part[(size_t)b * E_DIM + t * 4] = acc;
}

__global__ void t1red_k(const float* __restrict__ part, const float* __restrict__ bo,
                        float* __restrict__ t1)
{
  int j = blockIdx.x * 256 + threadIdx.x;
  float s = bo[j];
  for (int b = 0; b < 8; ++b) s += part[(size_t)b * E_DIM + j];
  t1[j] = s;
}

__global__ __launch_bounds__(256)
void matf_k(const float* __restrict__ W, const float* __restrict__ G,
            float* __restrict__ out)
{
  int k = blockIdx.x * 4 + (threadIdx.x >> 6);
  int lane = threadIdx.x & 63;
  float a0 = 0.f, a1 = 0.f, a2 = 0.f, a3 = 0.f, a4 = 0.f, a5 = 0.f, a6 = 0.f, a7 = 0.f;
  for (int m = lane; m < E_DIM; m += 64) {
    float w = W[(size_t)k * E_DIM + m];
    const float* gm = &G[m * 8];
    a0 = __builtin_fmaf(w, gm[0], a0); a1 = __builtin_fmaf(w, gm[1], a1);
    a2 = __builtin_fmaf(w, gm[2], a2); a3 = __builtin_fmaf(w, gm[3], a3);
    a4 = __builtin_fmaf(w, gm[4], a4); a5 = __builtin_fmaf(w, gm[5], a5);
    a6 = __builtin_fmaf(w, gm[6], a6); a7 = __builtin_fmaf(w, gm[7], a7);
  }
  #pragma unroll
  for (int off = 32; off; off >>= 1) {
    a0 += __shfl_xor(a0, off); a1 += __shfl_xor(a1, off);
    a2 += __shfl_xor(a2, off); a3 += __shfl_xor(a3, off);
    a4 += __shfl_xor(a4, off); a5 += __shfl_xor(a5, off);
    a6 += __shfl_xor(a6, off); a7 += __shfl_xor(a7, off);
  }
  if (lane == 0) {
    float* o = &out[k * 8];
    o[0] = a0; o[1] = a1; o[2] = a2; o[3] = a3;
    o[4] = a4; o[5] = a5; o[6] = a6; o[7] = a7;
  }
}

__global__ __launch_bounds__(512)
void gbias_k(const float* __restrict__ t1, const float* __restrict__ Wg,
             const float* __restrict__ bg, float* __restrict__ gb)
{
  int e = threadIdx.x >> 6, lane = threadIdx.x & 63;
  float s = 0.f;
  for (int m = lane; m < E_DIM; m += 64) s = __builtin_fmaf(t1[m], Wg[m * 8 + e], s);
  #pragma unroll
  for (int off = 32; off; off >>= 1) s += __shfl_xor(s, off);
  if (lane == 0) gb[e] = s + bg[e];
}

// ---------------- gate: logits -> softmax -> top2 -> counts ----------------
__global__ __launch_bounds__(256)
void gate_k(const float* __restrict__ text, const float* __restrict__ G3,
            const float* __restrict__ gb, float* __restrict__ gate_out,
            int* __restrict__ topIdx, float* __restrict__ topW,
            int* __restrict__ counts)
{
  __shared__ __align__(16) float sT[E_DIM];
  __shared__ float lg[8];
  int b = blockIdx.x, t = threadIdx.x;
  *(f32x4*)&sT[t * 4] = *(const f32x4*)&text[(size_t)b * E_DIM + t * 4];
  __syncthreads();
  int wave = t >> 6, lane = t & 63;
  #pragma unroll
  for (int ei = 0; ei < 2; ++ei) {
    int e = wave * 2 + ei;
    float s = 0.f;
    for (int k = lane; k < E_DIM; k += 64) s = __builtin_fmaf(sT[k], G3[k * 8 + e], s);
    #pragma unroll
    for (int off = 32; off; off >>= 1) s += __shfl_down(s, off);
    if (lane == 0) lg[e] = s + gb[e];
  }
  __syncthreads();
  if (t == 0) {
    float p[8];
    float mx = lg[0];
    for (int i = 1; i < 8; i++) mx = fmaxf(mx, lg[i]);
    float den = 0.f;
    for (int i = 0; i < 8; i++) { p[i] = __expf(lg[i] - mx); den += p[i]; }
    float inv = 1.f / den;
    for (int i = 0; i < 8; i++) { p[i] *= inv; gate_out[(size_t)b * 8 + i] = p[i]; }
    int i1 = 0;
    for (int i = 1; i < 8; i++) if (p[i] > p[i1]) i1 = i;       // ties -> lower index
    int i2 = (i1 == 0) ? 1 : 0;
    for (int i = 0; i < 8; i++) if (i != i1 && p[i] > p[i2]) i2 = i;
    float ex = __expf(p[i2] - p[i1]);                            // softmax over top-2 probs
    float w1 = 1.f / (1.f + ex), w2 = ex / (1.f + ex);
    topIdx[b * 2] = i1; topIdx[b * 2 + 1] = i2;
    topW[b * 2] = w1;  topW[b * 2 + 1] = w2;
    atomicAdd(&counts[i1], 1);
    atomicAdd(&counts[i2], 1);
  }
}

__global__ void imp_k(const float* __restrict__ gate_out, float* __restrict__ imp)
{
  int e = blockIdx.x, t = threadIdx.x;
  float s = 0.f;
  for (int b = t; b < B_TOK; b += 256) s += gate_out[(size_t)b * 8 + e];
  __shared__ float red[256];
  red[t] = s; __syncthreads();
  for (int off = 128; off; off >>= 1) { if (t < off) red[t] += red[t + off]; __syncthreads(); }
  if (t == 0) imp[e] = red[0];
}

__global__ void loss_k(const float* __restrict__ imp, float* __restrict__ out_loss)
{
  if (threadIdx.x == 0 && blockIdx.x == 0) {
    float m = 0.f;
    for (int e = 0; e < 8; e++) m += imp[e];
    m *= 0.125f;
    float v = 0.f;
    for (int e = 0; e < 8; e++) { float d = imp[e] - m; v += d * d; }
    v /= 7.f;                                  // ddof=1
    out_loss[0] = 0.01f * v / (m * m);
  }
}

__global__ void zero_k(int* counts, int* cursor)
{
  int t = threadIdx.x;
  if (t < 8) { counts[t] = 0; cursor[t] = 0; }
}

// prefix-scan + compact 256-row tile table: meta = {nT, (e, rowBase, rows)*}
__global__ void scan_k(const int* __restrict__ counts, int* __restrict__ bases,
                       int* __restrict__ meta)
{
  if (threadIdx.x == 0) {
    int a = 0, nt = 0;
    for (int e = 0; e < 8; e++) {
      bases[e] = a;
      int c = counts[e];
      for (int j = 0; j < c; j += 256) {
        meta[1 + 3 * nt] = e;
        meta[2 + 3 * nt] = a + j;
        meta[3 + 3 * nt] = (c - j < 256) ? (c - j) : 256;
        nt++;
      }
      a += c;
    }
    meta[0] = nt;
  }
}

__global__ void fill_k(const int* __restrict__ topIdx, int* __restrict__ cursor,
                       const int* __restrict__ bases, int* __restrict__ perm,
                       int* __restrict__ slotOf)
{
  int b = blockIdx.x * 256 + threadIdx.x;
  if (b < B_TOK) {
    #pragma unroll
    for (int j = 0; j < 2; j++) {
      int e = topIdx[b * 2 + j];
      int pos = atomicAdd(&cursor[e], 1);
      int slot = bases[e] + pos;
      perm[slot] = b;
      slotOf[b * 2 + j] = slot;
    }
  }
}

// combine split-K expert partials + per-expert bias, weighted top-2 mix
__global__ __launch_bounds__(256)
void combine_k(const float* __restrict__ Yp, const int* __restrict__ slotOf,
               const int* __restrict__ topIdx, const float* __restrict__ topW,
               const float* __restrict__ b2, float* __restrict__ y)
{
  int b = blockIdx.x, t = threadIdx.x;
  int s0 = slotOf[b * 2], s1 = slotOf[b * 2 + 1];
  int e0 = topIdx[b * 2], e1 = topIdx[b * 2 + 1];
  float w0 = topW[b * 2], w1 = topW[b * 2 + 1];
  int c = t * 4;
  size_t P1 = (size_t)NSLOT * E_DIM;
  f32x4 x0 = *(const f32x4*)&Yp[(size_t)s0 * E_DIM + c];
  x0 += *(const f32x4*)&Yp[P1 + (size_t)s0 * E_DIM + c];
  x0 += *(const f32x4*)&b2[(size_t)e0 * E_DIM + c];
  f32x4 x1 = *(const f32x4*)&Yp[(size_t)s1 * E_DIM + c];
  x1 += *(const f32x4*)&Yp[P1 + (size_t)s1 * E_DIM + c];
  x1 += *(const f32x4*)&b2[(size_t)e1 * E_DIM + c];
  f32x4 r = x0 * w0 + x1 * w1;
  *(f32x4*)&y[(size_t)b * E_DIM + c] = r;
}

// ---------------- host ----------------
extern "C" void kernel_launch(void* const* d_in, const int* in_sizes, int n_in,
                              void* d_out, int out_size, void* d_ws, size_t ws_size,
                              hipStream_t stream)
{
  (void)in_sizes; (void)n_in; (void)out_size;
  const float* src   = (const float*)d_in[0];
  const float* tgt   = (const float*)d_in[1];
  const float* bgr   = (const float*)d_in[2];
  const float* image = (const float*)d_in[3];
  const float* text  = (const float*)d_in[4];
  const float* W_enc = (const float*)d_in[5];
  const float* b_enc = (const float*)d_in[6];
  const float* W_img = (const float*)d_in[7];
  const float* b_img = (const float*)d_in[8];
  // d_in[9..12]: Wq,bq,Wk,bk — dead (softmax over length-1 key axis == 1)
  const float* Wv    = (const float*)d_in[13];
  const float* bv    = (const float*)d_in[14];
  const float* Wo    = (const float*)d_in[15];
  const float* bo    = (const float*)d_in[16];
  const float* Wg    = (const float*)d_in[17];
  const float* bgg   = (const float*)d_in[18];
  const float* W1    = (const float*)d_in[19];
  const float* b1    = (const float*)d_in[20];
  const float* W2    = (const float*)d_in[21];
  const float* b2    = (const float*)d_in[22];

  float* out_y    = (float*)d_out;
  float* out_gate = out_y + (size_t)B_TOK * E_DIM;
  float* out_loss = out_gate + (size_t)B_TOK * N_EXPC;

  char* p = (char*)d_ws;
  auto alloc = [&](size_t bytes) { char* r = p; p += (bytes + 255) & ~(size_t)255; return r; };
  uint16_t* WencT = (uint16_t*)alloc((size_t)256 * IMGSZ * 2);
  uint16_t* WimgT = (uint16_t*)alloc((size_t)256 * E_DIM * 2);
  uint16_t* W1T   = (uint16_t*)alloc((size_t)N_EXPC * HID * E_DIM * 2);
  uint16_t* W2T   = (uint16_t*)alloc((size_t)N_EXPC * E_DIM * HID * 2);
  float* part  = (float*)alloc((size_t)8 * E_DIM * 4);
  float* g1c   = (float*)alloc((size_t)E_DIM * 8 * 4);
  float* G3    = (float*)alloc((size_t)E_DIM * 8 * 4);
  float* t1    = (float*)alloc(E_DIM * 4);
  float* gbv   = (float*)alloc(64 * 4);
  float* impb  = (float*)alloc(64 * 4);
  int*   topIdx = (int*)alloc(B_TOK * 2 * 4);
  float* topW   = (float*)alloc(B_TOK * 2 * 4);
  int*   slotOf = (int*)alloc(B_TOK * 2 * 4);
  int*   counts = (int*)alloc(64 * 4);
  int*   bases  = (int*)alloc(64 * 4);
  int*   cursor = (int*)alloc(64 * 4);
  int*   meta   = (int*)alloc((1 + 3 * (MAXT2 + 1)) * 4 + 64);
  int*   perm   = (int*)alloc(NSLOT * 4);
  uint16_t* xbf  = (uint16_t*)alloc((size_t)B_TOK * E_DIM * 2);
  uint16_t* Hbuf = (uint16_t*)alloc((size_t)NSLOT * HID * 2);
  // union region: enc partials (56 MB) then expert split-K partials Yp (64 MB)
  char* uni = alloc((size_t)2 * NSLOT * E_DIM * 4);
  float* Penc = (float*)uni;                               // 12 * B_TOK * 256 f32 = 48 MB
  float* Pimg = Penc + (size_t)12 * B_TOK * 256;           // +8 MB
  float* Yp   = (float*)uni;                               // reused after redu_k
  if ((size_t)(p - (char*)d_ws) > ws_size) return;   // ws too small: fail visibly

  zero_k<<<1, 64, 0, stream>>>(counts, cursor);

  // weight transposes (f32 [R][C] -> bf16 [C][R])
  transpose64<<<dim3(256 / 64, IMGSZ / 64, 1), 256, 0, stream>>>(W_enc, WencT, IMGSZ, 256);
  transpose64<<<dim3(256 / 64, E_DIM / 64, 1), 256, 0, stream>>>(W_img, WimgT, E_DIM, 256);
  transpose64<<<dim3(HID / 64, E_DIM / 64, 8), 256, 0, stream>>>(W1, W1T, E_DIM, HID);
  transpose64<<<dim3(E_DIM / 64, HID / 64, 8), 256, 0, stream>>>(W2, W2T, HID, E_DIM);

  // gate fold (f32, precision-critical): logits = text@(Wv@(Wo@Wg)) + ((bv@Wo+bo)@Wg + bg)
  bvwo_k<<<8, 256, 0, stream>>>(bv, Wo, part);
  t1red_k<<<4, 256, 0, stream>>>(part, bo, t1);
  matf_k<<<256, 256, 0, stream>>>(Wo, Wg, g1c);
  matf_k<<<256, 256, 0, stream>>>(Wv, g1c, G3);
  gbias_k<<<1, 512, 0, stream>>>(t1, Wg, bgg, gbv);
  gate_k<<<B_TOK, 256, 0, stream>>>(text, G3, gbv, out_gate, topIdx, topW, counts);
  imp_k<<<8, 256, 0, stream>>>(out_gate, impb);
  loss_k<<<1, 64, 0, stream>>>(impb, out_loss);
  scan_k<<<1, 64, 0, stream>>>(counts, bases, meta);
  fill_k<<<16, 256, 0, stream>>>(topIdx, cursor, bases, perm, slotOf);

  // visionFeatures x = [enc(s)|enc(t)|enc(bg)|silu(img@W_img+b)]
  gemm_enc<4><<<dim3(B_TOK / 128, 4, 12), 256, 0, stream>>>(
      src, tgt, bgr, IMGSZ, WencT, Penc, IMGSZ);
  gemm_enc<2><<<dim3(B_TOK / 128, 4, 2), 256, 0, stream>>>(
      image, image, image, E_DIM, WimgT, Pimg, E_DIM);
  redu_k<4, false><<<dim3(B_TOK / 4, 3), 256, 0, stream>>>(Penc, b_enc, xbf, 0);
  redu_k<2, true><<<dim3(B_TOK / 4, 1), 256, 0, stream>>>(Pimg, b_img, xbf, 768);

  // sparse top-2 expert MLPs: 256^2 deep-ledger schedule; L2 split-K=2 into Yp planes
  gemm256<3, true, HID / 256, 1><<<dim3(MAXT2 * (HID / 256)), 512, 0, stream>>>(
      xbf, W1T, Hbuf, HID, b1, E_DIM, meta, perm, (size_t)HID * E_DIM, HID, 0);
  gemm256<0, false, E_DIM / 256, 2><<<dim3(MAXT2 * (E_DIM / 256) * 2), 512, 0, stream>>>(
      Hbuf, W2T, Yp, E_DIM, b2, HID, meta, perm, (size_t)E_DIM * HID, E_DIM,
      (size_t)NSLOT * E_DIM);

  combine_k<<<B_TOK, 256, 0, stream>>>(Yp, slotOf, topIdx, topW, b2, out_y);
}

// Round 8
// 697.651 us; speedup vs baseline: 1.1351x; 1.1351x over previous
//
#include <hip/hip_runtime.h>
#include <hip/hip_bf16.h>
#include <stdint.h>

typedef __bf16 bf16_t;
typedef bf16_t bf16x8 __attribute__((ext_vector_type(8)));
typedef float f32x4 __attribute__((ext_vector_type(4)));

static constexpr int B_TOK  = 4096;
static constexpr int E_DIM  = 1024;
static constexpr int N_EXPC = 8;
static constexpr int HID    = 4096;
static constexpr int IMGSZ  = 4096;
static constexpr int NSLOT  = 2 * B_TOK;
static constexpr int NTIL   = 71;          // max 128-row tiles: 64 + 7 remainder tiles

#define DEVI __device__ __forceinline__

DEVI int imin(int a, int b) { return a < b ? a : b; }

DEVI uint16_t f2bf(float f) {
  union { float f; uint32_t u; } v; v.f = f;
  uint32_t u = v.u;
  return (uint16_t)((u + 0x7FFFu + ((u >> 16) & 1u)) >> 16);
}

DEVI void gload_lds16(const void* g, void* l) {
  __builtin_amdgcn_global_load_lds((const __attribute__((address_space(1))) void*)g,
                                   (__attribute__((address_space(3))) void*)l, 16, 0, 0);
}

template<int N> DEVI void waitv() {
  if constexpr (N == 0)       asm volatile("s_waitcnt vmcnt(0)" ::: "memory");
  else if constexpr (N == 2)  asm volatile("s_waitcnt vmcnt(2)" ::: "memory");
  else if constexpr (N == 4)  asm volatile("s_waitcnt vmcnt(4)" ::: "memory");
  else if constexpr (N == 5)  asm volatile("s_waitcnt vmcnt(5)" ::: "memory");
  else if constexpr (N == 8)  asm volatile("s_waitcnt vmcnt(8)" ::: "memory");
  else if constexpr (N == 10) asm volatile("s_waitcnt vmcnt(10)" ::: "memory");
}

#define BAR() do { __builtin_amdgcn_sched_barrier(0); __builtin_amdgcn_s_barrier(); \
                   __builtin_amdgcn_sched_barrier(0); } while (0)

#define MFMA16(a, b, c) __builtin_amdgcn_mfma_f32_16x16x32_bf16((a), (b), (c), 0, 0, 0)

// ---------------- transpose + convert: f32 [R][C] -> bf16 [C][R], 64x64 tiles ----------------
__global__ __launch_bounds__(256)
void transpose64(const float* __restrict__ in, uint16_t* __restrict__ out, int R, int C)
{
  __shared__ float tile[64][65];
  size_t off = (size_t)blockIdx.z * (size_t)R * (size_t)C;
  int c0 = blockIdx.x * 64, r0 = blockIdx.y * 64;
  int t = threadIdx.x;
  #pragma unroll
  for (int i = 0; i < 16; ++i) {
    int rr = i * 4 + (t >> 6), cc = t & 63;
    tile[rr][cc] = in[off + (size_t)(r0 + rr) * C + c0 + cc];
  }
  __syncthreads();
  #pragma unroll
  for (int i = 0; i < 8; ++i) {
    int c = i * 8 + (t >> 5), j = t & 31;
    ushort2 w;
    w.x = f2bf(tile[2 * j][c]);
    w.y = f2bf(tile[2 * j + 1][c]);
    *(ushort2*)&out[off + (size_t)(c0 + c) * R + r0 + 2 * j] = w;
  }
}

// ================= expert GEMM: round-4 proven 128x128, depth-2 counted-vmcnt =================
// C[M,N] = A[M,K] @ BT[N,K]^T (+bias, +activation)
// EPI: 0=f32(+bias), 3=gelu(exp-form)->bf16 ; TILED: 1D supertile raster + XCD swizzle
template<int BN, int EPI, bool GATHER, bool TILED, int NT>
__global__ __launch_bounds__(256, 3)
void gemm_p(const uint16_t* __restrict__ Ab, int lda,
            const uint16_t* __restrict__ BT, void* __restrict__ Cv, int ldc,
            const float* __restrict__ bias, int K,
            const int* __restrict__ meta, const int* __restrict__ perm,
            size_t bStride, int biasStride)
{
  constexpr int HN = BN / 2, FN = BN / 32;
  constexpr int OPS = (BN == 128 ? 4 : 3);
  int rowBase, rows, e, nt;
  if constexpr (TILED) {
    constexpr int TOTAL = NTIL * NT, Q = TOTAL / 8, FULLB = 64 * NT;
    int bid = blockIdx.x;
    int wg = (bid & 7) * Q + (bid >> 3);            // bijective-enough XCD swizzle
    int mtile;
    if (wg < FULLB) { int rem = wg % (8 * NT); mtile = (wg / (8 * NT)) * 8 + (rem & 7); nt = rem >> 3; }
    else            { int rem = wg - FULLB;    mtile = 64 + rem % 7;                    nt = rem / 7; }
    if (mtile >= meta[0]) return;
    e = meta[1 + 3 * mtile]; rowBase = meta[2 + 3 * mtile]; rows = meta[3 + 3 * mtile];
  } else {
    e = 0; rowBase = blockIdx.x * 128; rows = 128; nt = blockIdx.y;
  }
  const uint16_t* Bt = BT + (TILED ? (size_t)e * bStride : 0);
  const float* bi = bias + (TILED ? (size_t)e * (size_t)biasStride : 0);

  constexpr int ABUF = 8192;
  constexpr int BBUF = (BN == 128) ? 8192 : 4096;
  __shared__ __align__(16) char sAraw[3 * ABUF];
  __shared__ __align__(16) char sBraw[3 * BBUF];

  int t = threadIdx.x, wave = t >> 6, lane = t & 63;
  int wr = wave >> 1, wc = wave & 1;

  int rB = t >> 2;
  int slB = ((t & 3) ^ (rB & 3)) * 8;
  const uint16_t* gB0 = Bt + (size_t)(nt * BN + rB) * K + slB;
  const uint16_t* gB1 = Bt + (size_t)(nt * BN + rB + 64) * K + slB;   // BN==128 only

  int r0 = t >> 2, r1 = r0 + 64;
  int sl = ((t & 3) ^ (r0 & 3)) * 8;
  int car0, car1;
  if constexpr (TILED) {
    int rr0 = imin(r0, rows - 1), rr1 = imin(r1, rows - 1);
    car0 = GATHER ? perm[rowBase + rr0] : rowBase + rr0;
    car1 = GATHER ? perm[rowBase + rr1] : rowBase + rr1;
  } else { car0 = rowBase + r0; car1 = rowBase + r1; }
  const uint16_t* gA0 = Ab + (size_t)car0 * lda + sl;
  const uint16_t* gA1 = Ab + (size_t)car1 * lda + sl;

  char* laW = sAraw + wave * 1024;
  char* lbW = sBraw + wave * 1024;
  auto STAGE = [&](int kt, int c) {
    int ko = kt << 5;
    char* la = laW + c * ABUF;
    char* lb = lbW + c * BBUF;
    gload_lds16(gA0 + ko, la);
    gload_lds16(gA1 + ko, la + 4096);
    gload_lds16(gB0 + ko, lb);
    if constexpr (BN == 128) gload_lds16(gB1 + ko, lb + 4096);
  };

  f32x4 acc[4][FN];
  #pragma unroll
  for (int m = 0; m < 4; m++)
    #pragma unroll
    for (int n = 0; n < FN; n++)
      acc[m][n] = f32x4{0.f, 0.f, 0.f, 0.f};

  STAGE(0, 0);
  STAGE(1, 1);

  int fr = lane & 15;
  int rdoff = ((lane >> 4) ^ (lane & 3)) * 16;
  int c0 = 0, c2 = 2;
  int nk = K >> 5;

  for (int kt = 0; kt < nk; ++kt) {
    if (kt + 2 < nk) { STAGE(kt + 2, c2); waitv<2 * OPS>(); }
    else if (kt + 1 < nk) waitv<OPS>();
    else waitv<0>();
    BAR();

    const char* bA = sAraw + c0 * ABUF;
    const char* bB = sBraw + c0 * BBUF;
    bf16x8 af[4], bfr[FN];
    #pragma unroll
    for (int m = 0; m < 4; m++)
      af[m] = *(const bf16x8*)(bA + (wr * 64 + m * 16 + fr) * 64 + rdoff);
    #pragma unroll
    for (int n = 0; n < FN; n++)
      bfr[n] = *(const bf16x8*)(bB + (wc * HN + n * 16 + fr) * 64 + rdoff);
    #pragma unroll
    for (int m = 0; m < 4; m++)
      #pragma unroll
      for (int n = 0; n < FN; n++)
        acc[m][n] = MFMA16(af[m], bfr[n], acc[m][n]);

    BAR();
    c0 = (c0 == 2) ? 0 : c0 + 1;
    c2 = (c2 == 2) ? 0 : c2 + 1;
  }

  // epilogue: C/D layout col=lane&15, row=(lane>>4)*4+reg (m89-verified)
  #pragma unroll
  for (int m = 0; m < 4; m++) {
    int lrow = wr * 64 + m * 16 + (lane >> 4) * 4;
    #pragma unroll
    for (int n = 0; n < FN; n++) {
      int col = nt * BN + wc * HN + n * 16 + (lane & 15);
      float bval = bi[col];
      #pragma unroll
      for (int r = 0; r < 4; r++) {
        int lr = lrow + r;
        if (TILED && lr >= rows) continue;
        float v = acc[m][n][r] + bval;
        size_t cr = (size_t)(rowBase + lr) * ldc + col;
        if (EPI == 3) {   // gelu(tanh) == v * sigmoid(1.5957691*(v + 0.044715 v^3))
          float u = v + 0.044715f * v * v * v;
          v = v / (1.f + __expf(-1.5957691216057308f * u));
          ((uint16_t*)Cv)[cr] = f2bf(v);
        } else {
          ((float*)Cv)[cr] = v;
        }
      }
    }
  }
}

// ================= enc/img GEMM: reg-A streaming (memory-bound regime) =================
// BM=64, BN=128, 4 waves (wave owns 16 rows x 128 cols). A f32 loaded DIRECT to regs in
// MFMA fragment layout (lane: row=l&15, k=(l>>4)*8..+8; lanes l,l+16,l+32,l+48 = one 128B
// contiguous row chunk) with 2-step prefetch. B bf16 staged in LDS, 3-buffer counted-vmcnt.
// Output: raw f32 split-K partial P[z][B_TOK][256].
template<int SPLITK>
__global__ __launch_bounds__(256, 3)
void gemm_encR(const float* __restrict__ F0, const float* __restrict__ F1,
               const float* __restrict__ F2, int lda,
               const uint16_t* __restrict__ BT, float* __restrict__ P, int K)
{
  int z = blockIdx.z, br = z / SPLITK, kc = z % SPLITK;
  const float* Af = (br == 0) ? F0 : (br == 1) ? F1 : F2;
  int Kc = K / SPLITK, k0 = kc * Kc;
  int rowBase = blockIdx.x * 64, nt = blockIdx.y;

  __shared__ __align__(16) char sB[3 * 8192];
  int t = threadIdx.x, wave = t >> 6, lane = t & 63;
  int fr = lane & 15, q4 = lane >> 4;

  // A direct-to-reg fragment pointer
  const float* gA = Af + (size_t)(rowBase + wave * 16 + fr) * lda + k0 + q4 * 8;

  // B staging: 2 gloads/wave/K-step covering 128 rows x 64B; write-swizzle (t&3)^(row&3)
  int rloc = t >> 2;
  int ssw = ((t & 3) ^ (rloc & 3)) * 8;
  const uint16_t* gB0 = BT + (size_t)(nt * 128 + rloc) * K + k0 + ssw;
  const uint16_t* gB1 = gB0 + (size_t)64 * K;

  auto STB = [&](int kt, int c) {
    gload_lds16(gB0 + kt * 32, sB + c * 8192 + wave * 1024);
    gload_lds16(gB1 + kt * 32, sB + c * 8192 + 4096 + wave * 1024);
  };

  f32x4 acc[8];
  #pragma unroll
  for (int n = 0; n < 8; ++n) acc[n] = f32x4{0.f, 0.f, 0.f, 0.f};

  int nk = Kc >> 5;                 // even for all our shapes (32 / 16)
  STB(0, 0); STB(1, 1);
  f32x4 aE0 = *(const f32x4*)(gA),      aE1 = *(const f32x4*)(gA + 4);
  f32x4 aO0 = *(const f32x4*)(gA + 32), aO1 = *(const f32x4*)(gA + 36);
  int c0 = 0, c2 = 2;
  int bRow = (q4 ^ (fr & 3)) * 16;  // read-side slice XOR (matches write swizzle)

  auto step = [&](int kt, f32x4& aX0, f32x4& aX1) {
    bool m2 = kt + 2 < nk;
    if (m2) STB(kt + 2, c2);
    bf16x8 a;
    a[0] = (bf16_t)aX0[0]; a[1] = (bf16_t)aX0[1]; a[2] = (bf16_t)aX0[2]; a[3] = (bf16_t)aX0[3];
    a[4] = (bf16_t)aX1[0]; a[5] = (bf16_t)aX1[1]; a[6] = (bf16_t)aX1[2]; a[7] = (bf16_t)aX1[3];
    int kp = m2 ? kt + 2 : kt;                       // clamped prefetch (no OOB)
    aX0 = *(const f32x4*)(gA + kp * 32);
    aX1 = *(const f32x4*)(gA + kp * 32 + 4);
    if (m2) waitv<10>(); else waitv<0>();            // B(kt) retired (<=10 newer vmem ops)
    BAR();
    const char* bb = sB + c0 * 8192;
    bf16x8 bfr[8];
    #pragma unroll
    for (int n = 0; n < 8; ++n)
      bfr[n] = *(const bf16x8*)(bb + n * 1024 + fr * 64 + bRow);
    #pragma unroll
    for (int n = 0; n < 8; ++n) acc[n] = MFMA16(a, bfr[n], acc[n]);
    BAR();
    c0 = (c0 == 2) ? 0 : c0 + 1;
    c2 = (c2 == 2) ? 0 : c2 + 1;
  };

  for (int kt = 0; kt < nk; kt += 2) {
    step(kt, aE0, aE1);
    step(kt + 1, aO0, aO1);
  }

  // epilogue: raw f32 partials
  #pragma unroll
  for (int n = 0; n < 8; ++n) {
    int col = nt * 128 + n * 16 + fr;
    #pragma unroll
    for (int r = 0; r < 4; ++r) {
      int row = rowBase + wave * 16 + q4 * 4 + r;
      P[((size_t)z * B_TOK + row) * 256 + col] = acc[n][r];
    }
  }
}

// reduce split-K partials + bias (+silu) -> bf16 columns of xbf
template<int SK, bool SILU>
__global__ __launch_bounds__(256)
void redu_k(const float* __restrict__ P, const float* __restrict__ bias,
            uint16_t* __restrict__ xb, int colBase)
{
  int br = blockIdx.y;
  int row = blockIdx.x * 4 + (threadIdx.x >> 6);
  int c4 = (threadIdx.x & 63) * 4;
  f32x4 s = *(const f32x4*)&bias[c4];
  const float* p = P + ((size_t)br * SK * B_TOK + row) * 256 + c4;
  #pragma unroll
  for (int kc = 0; kc < SK; ++kc)
    s += *(const f32x4*)(p + (size_t)kc * B_TOK * 256);
  if (SILU) {
    #pragma unroll
    for (int j = 0; j < 4; ++j) s[j] = s[j] / (1.f + __expf(-s[j]));
  }
  ushort4 o;
  o.x = f2bf(s[0]); o.y = f2bf(s[1]); o.z = f2bf(s[2]); o.w = f2bf(s[3]);
  *(ushort4*)&xb[(size_t)row * E_DIM + colBase + br * 256 + c4] = o;
}

// ---------------- gate-path fold (all f32, parallelized) ----------------
__global__ __launch_bounds__(256)
void bvwo_k(const float* __restrict__ bv, const float* __restrict__ Wo,
            float* __restrict__ part)
{
  int b = blockIdx.x, t = threadIdx.x;
  f32x4 acc = {0.f, 0.f, 0.f, 0.f};
  for (int k = b * 128; k < b * 128 + 128; ++k) {
    float s = bv[k];
    f32x4 w = *(const f32x4*)&Wo[(size_t)k * E_DIM + t * 4];
    acc[0] = __builtin_fmaf(s, w[0], acc[0]);
    acc[1] = __builtin_fmaf(s, w[1], acc[1]);
    acc[2] = __builtin_fmaf(s, w[2], acc[2]);
    acc[3] = __builtin_fmaf(s, w[3], acc[3]);
  }
  *(f32x4*)&part[(size_t)b * E_DIM + t * 4] = acc;
}

__global__ void t1red_k(const float* __restrict__ part, const float* __restrict__ bo,
                        float* __restrict__ t1)
{
  int j = blockIdx.x * 256 + threadIdx.x;
  float s = bo[j];
  for (int b = 0; b < 8; ++b) s += part[(size_t)b * E_DIM + j];
  t1[j] = s;
}

__global__ __launch_bounds__(256)
void matf_k(const float* __restrict__ W, const float* __restrict__ G,
            float* __restrict__ out)
{
  int k = blockIdx.x * 4 + (threadIdx.x >> 6);
  int lane = threadIdx.x & 63;
  float a0 = 0.f, a1 = 0.f, a2 = 0.f, a3 = 0.f, a4 = 0.f, a5 = 0.f, a6 = 0.f, a7 = 0.f;
  for (int m = lane; m < E_DIM; m += 64) {
    float w = W[(size_t)k * E_DIM + m];
    const float* gm = &G[m * 8];
    a0 = __builtin_fmaf(w, gm[0], a0); a1 = __builtin_fmaf(w, gm[1], a1);
    a2 = __builtin_fmaf(w, gm[2], a2); a3 = __builtin_fmaf(w, gm[3], a3);
    a4 = __builtin_fmaf(w, gm[4], a4); a5 = __builtin_fmaf(w, gm[5], a5);
    a6 = __builtin_fmaf(w, gm[6], a6); a7 = __builtin_fmaf(w, gm[7], a7);
  }
  #pragma unroll
  for (int off = 32; off; off >>= 1) {
    a0 += __shfl_xor(a0, off); a1 += __shfl_xor(a1, off);
    a2 += __shfl_xor(a2, off); a3 += __shfl_xor(a3, off);
    a4 += __shfl_xor(a4, off); a5 += __shfl_xor(a5, off);
    a6 += __shfl_xor(a6, off); a7 += __shfl_xor(a7, off);
  }
  if (lane == 0) {
    float* o = &out[k * 8];
    o[0] = a0; o[1] = a1; o[2] = a2; o[3] = a3;
    o[4] = a4; o[5] = a5; o[6] = a6; o[7] = a7;
  }
}

__global__ __launch_bounds__(512)
void gbias_k(const float* __restrict__ t1, const float* __restrict__ Wg,
             const float* __restrict__ bg, float* __restrict__ gb)
{
  int e = threadIdx.x >> 6, lane = threadIdx.x & 63;
  float s = 0.f;
  for (int m = lane; m < E_DIM; m += 64) s = __builtin_fmaf(t1[m], Wg[m * 8 + e], s);
  #pragma unroll
  for (int off = 32; off; off >>= 1) s += __shfl_xor(s, off);
  if (lane == 0) gb[e] = s + bg[e];
}

// ---------------- gate: logits -> softmax -> top2 -> counts ----------------
__global__ __launch_bounds__(256)
void gate_k(const float* __restrict__ text, const float* __restrict__ G3,
            const float* __restrict__ gb, float* __restrict__ gate_out,
            int* __restrict__ topIdx, float* __restrict__ topW,
            int* __restrict__ counts)
{
  __shared__ __align__(16) float sT[E_DIM];
  __shared__ float lg[8];
  int b = blockIdx.x, t = threadIdx.x;
  *(f32x4*)&sT[t * 4] = *(const f32x4*)&text[(size_t)b * E_DIM + t * 4];
  __syncthreads();
  int wave = t >> 6, lane = t & 63;
  #pragma unroll
  for (int ei = 0; ei < 2; ++ei) {
    int e = wave * 2 + ei;
    float s = 0.f;
    for (int k = lane; k < E_DIM; k += 64) s = __builtin_fmaf(sT[k], G3[k * 8 + e], s);
    #pragma unroll
    for (int off = 32; off; off >>= 1) s += __shfl_down(s, off);
    if (lane == 0) lg[e] = s + gb[e];
  }
  __syncthreads();
  if (t == 0) {
    float p[8];
    float mx = lg[0];
    for (int i = 1; i < 8; i++) mx = fmaxf(mx, lg[i]);
    float den = 0.f;
    for (int i = 0; i < 8; i++) { p[i] = __expf(lg[i] - mx); den += p[i]; }
    float inv = 1.f / den;
    for (int i = 0; i < 8; i++) { p[i] *= inv; gate_out[(size_t)b * 8 + i] = p[i]; }
    int i1 = 0;
    for (int i = 1; i < 8; i++) if (p[i] > p[i1]) i1 = i;       // ties -> lower index
    int i2 = (i1 == 0) ? 1 : 0;
    for (int i = 0; i < 8; i++) if (i != i1 && p[i] > p[i2]) i2 = i;
    float ex = __expf(p[i2] - p[i1]);                            // softmax over top-2 probs
    float w1 = 1.f / (1.f + ex), w2 = ex / (1.f + ex);
    topIdx[b * 2] = i1; topIdx[b * 2 + 1] = i2;
    topW[b * 2] = w1;  topW[b * 2 + 1] = w2;
    atomicAdd(&counts[i1], 1);
    atomicAdd(&counts[i2], 1);
  }
}

__global__ void imp_k(const float* __restrict__ gate_out, float* __restrict__ imp)
{
  int e = blockIdx.x, t = threadIdx.x;
  float s = 0.f;
  for (int b = t; b < B_TOK; b += 256) s += gate_out[(size_t)b * 8 + e];
  __shared__ float red[256];
  red[t] = s; __syncthreads();
  for (int off = 128; off; off >>= 1) { if (t < off) red[t] += red[t + off]; __syncthreads(); }
  if (t == 0) imp[e] = red[0];
}

__global__ void loss_k(const float* __restrict__ imp, float* __restrict__ out_loss)
{
  if (threadIdx.x == 0 && blockIdx.x == 0) {
    float m = 0.f;
    for (int e = 0; e < 8; e++) m += imp[e];
    m *= 0.125f;
    float v = 0.f;
    for (int e = 0; e < 8; e++) { float d = imp[e] - m; v += d * d; }
    v /= 7.f;                                  // ddof=1
    out_loss[0] = 0.01f * v / (m * m);
  }
}

__global__ void zero_k(int* counts, int* cursor)
{
  int t = threadIdx.x;
  if (t < 8) { counts[t] = 0; cursor[t] = 0; }
}

// prefix-scan + compact 128-row tile table: meta = {nT, (e, rowBase, rows)*}
__global__ void scan_k(const int* __restrict__ counts, int* __restrict__ bases,
                       int* __restrict__ meta)
{
  if (threadIdx.x == 0) {
    int a = 0, nt = 0;
    for (int e = 0; e < 8; e++) {
      bases[e] = a;
      int c = counts[e];
      for (int j = 0; j < c; j += 128) {
        meta[1 + 3 * nt] = e;
        meta[2 + 3 * nt] = a + j;
        meta[3 + 3 * nt] = (c - j < 128) ? (c - j) : 128;
        nt++;
      }
      a += c;
    }
    meta[0] = nt;
  }
}

__global__ void fill_k(const int* __restrict__ topIdx, int* __restrict__ cursor,
                       const int* __restrict__ bases, int* __restrict__ perm,
                       int* __restrict__ slotOf)
{
  int b = blockIdx.x * 256 + threadIdx.x;
  if (b < B_TOK) {
    #pragma unroll
    for (int j = 0; j < 2; j++) {
      int e = topIdx[b * 2 + j];
      int pos = atomicAdd(&cursor[e], 1);
      int slot = bases[e] + pos;
      perm[slot] = b;
      slotOf[b * 2 + j] = slot;
    }
  }
}

// weighted top-2 mix (bias already added inside expert L2 GEMM)
__global__ __launch_bounds__(256)
void combine_k(const float* __restrict__ Yg, const int* __restrict__ slotOf,
               const float* __restrict__ topW, float* __restrict__ y)
{
  int b = blockIdx.x, t = threadIdx.x;
  int s0 = slotOf[b * 2], s1 = slotOf[b * 2 + 1];
  float w0 = topW[b * 2], w1 = topW[b * 2 + 1];
  f32x4 a = *(const f32x4*)&Yg[(size_t)s0 * E_DIM + t * 4];
  f32x4 c = *(const f32x4*)&Yg[(size_t)s1 * E_DIM + t * 4];
  f32x4 r = a * w0 + c * w1;
  *(f32x4*)&y[(size_t)b * E_DIM + t * 4] = r;
}

// ---------------- host ----------------
extern "C" void kernel_launch(void* const* d_in, const int* in_sizes, int n_in,
                              void* d_out, int out_size, void* d_ws, size_t ws_size,
                              hipStream_t stream)
{
  (void)in_sizes; (void)n_in; (void)out_size;
  const float* src   = (const float*)d_in[0];
  const float* tgt   = (const float*)d_in[1];
  const float* bgr   = (const float*)d_in[2];
  const float* image = (const float*)d_in[3];
  const float* text  = (const float*)d_in[4];
  const float* W_enc = (const float*)d_in[5];
  const float* b_enc = (const float*)d_in[6];
  const float* W_img = (const float*)d_in[7];
  const float* b_img = (const float*)d_in[8];
  // d_in[9..12]: Wq,bq,Wk,bk — dead (softmax over length-1 key axis == 1)
  const float* Wv    = (const float*)d_in[13];
  const float* bv    = (const float*)d_in[14];
  const float* Wo    = (const float*)d_in[15];
  const float* bo    = (const float*)d_in[16];
  const float* Wg    = (const float*)d_in[17];
  const float* bgg   = (const float*)d_in[18];
  const float* W1    = (const float*)d_in[19];
  const float* b1    = (const float*)d_in[20];
  const float* W2    = (const float*)d_in[21];
  const float* b2    = (const float*)d_in[22];

  float* out_y    = (float*)d_out;
  float* out_gate = out_y + (size_t)B_TOK * E_DIM;
  float* out_loss = out_gate + (size_t)B_TOK * N_EXPC;

  char* p = (char*)d_ws;
  auto alloc = [&](size_t bytes) { char* r = p; p += (bytes + 255) & ~(size_t)255; return r; };
  uint16_t* WencT = (uint16_t*)alloc((size_t)256 * IMGSZ * 2);
  uint16_t* WimgT = (uint16_t*)alloc((size_t)256 * E_DIM * 2);
  uint16_t* W1T   = (uint16_t*)alloc((size_t)N_EXPC * HID * E_DIM * 2);
  uint16_t* W2T   = (uint16_t*)alloc((size_t)N_EXPC * E_DIM * HID * 2);
  float* part  = (float*)alloc((size_t)8 * E_DIM * 4);
  float* g1c   = (float*)alloc((size_t)E_DIM * 8 * 4);
  float* G3    = (float*)alloc((size_t)E_DIM * 8 * 4);
  float* t1    = (float*)alloc(E_DIM * 4);
  float* gbv   = (float*)alloc(64 * 4);
  float* impb  = (float*)alloc(64 * 4);
  int*   topIdx = (int*)alloc(B_TOK * 2 * 4);
  float* topW   = (float*)alloc(B_TOK * 2 * 4);
  int*   slotOf = (int*)alloc(B_TOK * 2 * 4);
  int*   counts = (int*)alloc(64 * 4);
  int*   bases  = (int*)alloc(64 * 4);
  int*   cursor = (int*)alloc(64 * 4);
  int*   meta   = (int*)alloc((1 + 3 * (NTIL + 1)) * 4 + 64);
  int*   perm   = (int*)alloc(NSLOT * 4);
  uint16_t* xbf  = (uint16_t*)alloc((size_t)B_TOK * E_DIM * 2);
  uint16_t* Hbuf = (uint16_t*)alloc((size_t)NSLOT * HID * 2);
  // union region: enc partials (56 MB) then expert output Yg f32 (32 MB)
  char* uni = alloc((size_t)14 * B_TOK * 256 * 4);
  float* Penc = (float*)uni;                               // 12 planes * 4 MB
  float* Pimg = Penc + (size_t)12 * B_TOK * 256;           // 2 planes
  float* Yg   = (float*)uni;                               // reused after redu_k
  if ((size_t)(p - (char*)d_ws) > ws_size) return;   // ws too small: fail visibly

  zero_k<<<1, 64, 0, stream>>>(counts, cursor);

  // weight transposes (f32 [R][C] -> bf16 [C][R])
  transpose64<<<dim3(256 / 64, IMGSZ / 64, 1), 256, 0, stream>>>(W_enc, WencT, IMGSZ, 256);
  transpose64<<<dim3(256 / 64, E_DIM / 64, 1), 256, 0, stream>>>(W_img, WimgT, E_DIM, 256);
  transpose64<<<dim3(HID / 64, E_DIM / 64, 8), 256, 0, stream>>>(W1, W1T, E_DIM, HID);
  transpose64<<<dim3(E_DIM / 64, HID / 64, 8), 256, 0, stream>>>(W2, W2T, HID, E_DIM);

  // gate fold (f32, precision-critical): logits = text@(Wv@(Wo@Wg)) + ((bv@Wo+bo)@Wg + bg)
  bvwo_k<<<8, 256, 0, stream>>>(bv, Wo, part);
  t1red_k<<<4, 256, 0, stream>>>(part, bo, t1);
  matf_k<<<256, 256, 0, stream>>>(Wo, Wg, g1c);
  matf_k<<<256, 256, 0, stream>>>(Wv, g1c, G3);
  gbias_k<<<1, 512, 0, stream>>>(t1, Wg, bgg, gbv);
  gate_k<<<B_TOK, 256, 0, stream>>>(text, G3, gbv, out_gate, topIdx, topW, counts);
  imp_k<<<8, 256, 0, stream>>>(out_gate, impb);
  loss_k<<<1, 64, 0, stream>>>(impb, out_loss);
  scan_k<<<1, 64, 0, stream>>>(counts, bases, meta);
  fill_k<<<16, 256, 0, stream>>>(topIdx, cursor, bases, perm, slotOf);

  // visionFeatures x = [enc(s)|enc(t)|enc(bg)|silu(img@W_img+b)]  (reg-A streaming GEMM)
  gemm_encR<4><<<dim3(B_TOK / 64, 2, 12), 256, 0, stream>>>(
      src, tgt, bgr, IMGSZ, WencT, Penc, IMGSZ);
  gemm_encR<2><<<dim3(B_TOK / 64, 2, 2), 256, 0, stream>>>(
      image, image, image, E_DIM, WimgT, Pimg, E_DIM);
  redu_k<4, false><<<dim3(B_TOK / 4, 3), 256, 0, stream>>>(Penc, b_enc, xbf, 0);
  redu_k<2, true><<<dim3(B_TOK / 4, 1), 256, 0, stream>>>(Pimg, b_img, xbf, 768);

  // sparse top-2 expert MLPs: round-4 proven 128^2 supertile-raster kernels
  gemm_p<128, 3, true, true, HID / 128><<<dim3(NTIL * (HID / 128)), 256, 0, stream>>>(
      xbf, E_DIM, W1T, Hbuf, HID, b1, E_DIM, meta, perm, (size_t)HID * E_DIM, HID);
  gemm_p<128, 0, false, true, E_DIM / 128><<<dim3(NTIL * (E_DIM / 128)), 256, 0, stream>>>(
      Hbuf, HID, W2T, Yg, E_DIM, b2, HID, meta, perm, (size_t)E_DIM * HID, E_DIM);

  combine_k<<<B_TOK, 256, 0, stream>>>(Yg, slotOf, topW, out_y);
}